// Round 14
// baseline (561.621 us; speedup 1.0000x reference)
//
#include <hip/hip_runtime.h>
#include <math.h>

#define NN 50000
#define NE 800000

typedef float f32x4 __attribute__((ext_vector_type(4)));
typedef short s16x8 __attribute__((ext_vector_type(8)));
typedef short s16x4 __attribute__((ext_vector_type(4)));
typedef unsigned int u32;

__device__ __forceinline__ short f2bf(float f) {
    union { float f; u32 u; } v; v.f = f;
    u32 u = v.u;
    u += 0x7FFF + ((u >> 16) & 1);   // round-to-nearest-even
    return (short)(u >> 16);
}

__device__ __forceinline__ float u2f(u32 u) {
    union { u32 u; float f; } v; v.u = u; return v.f;
}

__device__ __forceinline__ s16x8 cvt8(f32x4 a, f32x4 b) {
    s16x8 r;
    r[0] = f2bf(a[0]); r[1] = f2bf(a[1]); r[2] = f2bf(a[2]); r[3] = f2bf(a[3]);
    r[4] = f2bf(b[0]); r[5] = f2bf(b[1]); r[6] = f2bf(b[2]); r[7] = f2bf(b[3]);
    return r;
}

__device__ __forceinline__ float gelu_exact(float x) {
    return 0.5f * x * (1.0f + erff(x * 0.70710678118654752f));
}

// tanh-form GELU (certified r8)
__device__ __forceinline__ float gelu_fast(float x) {
    const float z = 1.5957691216f * x * (1.0f + 0.044715f * x * x);
    return x * __builtin_amdgcn_rcpf(1.0f + __expf(-z));
}

// ---- prep: nf->bf16 + weights in MFMA-fragment order (r13 exact) ----
__global__ __launch_bounds__(256) void prep_e(
    const float* __restrict__ nf, const float* __restrict__ ew1,
    const float* __restrict__ ew2,
    short* __restrict__ nfh, short* __restrict__ w1f, short* __restrict__ w2f)
{
    int idx = blockIdx.x * 256 + threadIdx.x;
    if (idx < NN * 64) nfh[idx] = f2bf(nf[idx]);
    if (idx < 24576) {                       // w1f: 6 ks * 8 ct * 512
        const int m = idx >> 9, r = idx & 511;
        const int lane = r >> 3, j = r & 7;
        const int ks = m >> 3, ct = m & 7;
        const int k = ks * 32 + (lane >> 4) * 8 + j;
        const int c = ct * 16 + (lane & 15);
        w1f[idx] = f2bf(ew1[k * 128 + c]);
    } else if (idx < 32768) {                // w2f: 4 ks * 4 ct * 512
        const int i = idx - 24576;
        const int m = i >> 9, r = i & 511;
        const int lane = r >> 3, j = r & 7;
        const int ks = m >> 2, ct = m & 3;
        const int k = ks * 32 + (lane >> 4) * 8 + j;
        const int c = ct * 16 + (lane & 15);
        w2f[i] = f2bf(ew2[k * 64 + c]);
    }
}

// ---- edge kernel: r13 + 32 edges/wave (r8-certified 2-row-group form) ----
// B-fragment loads (64/wave) now amortize over 32 edges instead of 16:
// chip-wide B vmem 3.2 GB -> 1.6 GB. LDS 53.2 KB -> 3 blocks/CU (~37% occ,
// proven non-binding in r8/r10/r11).
__global__ __launch_bounds__(256) void edge_k(
    const short* __restrict__ nfh, const int* __restrict__ ei,
    const float* __restrict__ ef,
    const short* __restrict__ w1f, const float* __restrict__ b1,
    const short* __restrict__ w2f, const float* __restrict__ b2,
    const float* __restrict__ gamma, const float* __restrict__ beta,
    float* __restrict__ eout, float* __restrict__ agg, float* __restrict__ cnt)
{
    __shared__ short h_lds[128][136];        // 34816 B; aliased float[128][68]
    __shared__ short ef_lds[128][72];        // 18432 B; bf16 ef rows
    const int tid  = threadIdx.x;
    const int wave = tid >> 6, lane = tid & 63;
    const int lo = lane & 15, hi = lane >> 4;
    const int eb = blockIdx.x * 128 + wave * 32;

    const int ar0 = eb + lo, ar1 = eb + 16 + lo;
    const int s0 = ei[ar0], s1 = ei[ar1];
    const int d0 = ei[NE + ar0], d1 = ei[NE + ar1];

    const short* pS0 = nfh + (size_t)s0 * 64;
    const short* pS1 = nfh + (size_t)s1 * 64;
    const short* pD0 = nfh + (size_t)d0 * 64;
    const short* pD1 = nfh + (size_t)d1 * 64;
    const float* pE0 = ef + (size_t)ar0 * 64;
    const float* pE1 = ef + (size_t)ar1 * 64;
    const int o0 = hi * 8, o1 = 32 + hi * 8;

    f32x4 acc[2][8];
#pragma unroll
    for (int i = 0; i < 2; ++i)
#pragma unroll
        for (int j = 0; j < 8; ++j)
#pragma unroll
            for (int q = 0; q < 4; ++q) acc[i][j][q] = 0.0f;

    // nf segments: bf16 gather, 2 row-groups share each B-fragment load
#define KSTEP_H(P0, P1, OFF, KS)                                                \
    {                                                                           \
        s16x8 fa0 = *(const s16x8*)((P0) + (OFF));                              \
        s16x8 fa1 = *(const s16x8*)((P1) + (OFF));                              \
        _Pragma("unroll")                                                       \
        for (int ct = 0; ct < 8; ++ct) {                                        \
            s16x8 b = *(const s16x8*)(w1f + (((KS) * 8 + ct) << 9) + lane * 8); \
            acc[0][ct] = __builtin_amdgcn_mfma_f32_16x16x32_bf16(fa0, b, acc[0][ct], 0, 0, 0); \
            acc[1][ct] = __builtin_amdgcn_mfma_f32_16x16x32_bf16(fa1, b, acc[1][ct], 0, 0, 0); \
        }                                                                       \
    }
    // ef segments: f32 load + cvt + stash bf16 rows (both groups)
#define KSTEP_E(OFF, KS, KO)                                                    \
    {                                                                           \
        f32x4 x0l = *(const f32x4*)(pE0 + (OFF));                               \
        f32x4 x0h = *(const f32x4*)(pE0 + (OFF) + 4);                           \
        f32x4 x1l = *(const f32x4*)(pE1 + (OFF));                               \
        f32x4 x1h = *(const f32x4*)(pE1 + (OFF) + 4);                           \
        s16x8 fa0 = cvt8(x0l, x0h), fa1 = cvt8(x1l, x1h);                       \
        s16x4 t0, t1;                                                           \
        t0[0]=fa0[0]; t0[1]=fa0[1]; t0[2]=fa0[2]; t0[3]=fa0[3];                 \
        t1[0]=fa0[4]; t1[1]=fa0[5]; t1[2]=fa0[6]; t1[3]=fa0[7];                 \
        *(s16x4*)&ef_lds[wave * 32 + lo][(KO) + hi * 8]     = t0;               \
        *(s16x4*)&ef_lds[wave * 32 + lo][(KO) + hi * 8 + 4] = t1;               \
        t0[0]=fa1[0]; t0[1]=fa1[1]; t0[2]=fa1[2]; t0[3]=fa1[3];                 \
        t1[0]=fa1[4]; t1[1]=fa1[5]; t1[2]=fa1[6]; t1[3]=fa1[7];                 \
        *(s16x4*)&ef_lds[wave * 32 + 16 + lo][(KO) + hi * 8]     = t0;          \
        *(s16x4*)&ef_lds[wave * 32 + 16 + lo][(KO) + hi * 8 + 4] = t1;          \
        _Pragma("unroll")                                                       \
        for (int ct = 0; ct < 8; ++ct) {                                        \
            s16x8 b = *(const s16x8*)(w1f + (((KS) * 8 + ct) << 9) + lane * 8); \
            acc[0][ct] = __builtin_amdgcn_mfma_f32_16x16x32_bf16(fa0, b, acc[0][ct], 0, 0, 0); \
            acc[1][ct] = __builtin_amdgcn_mfma_f32_16x16x32_bf16(fa1, b, acc[1][ct], 0, 0, 0); \
        }                                                                       \
    }

    KSTEP_H(pS0, pS1, o0, 0);    // k   0..31 : nf[src] 0..31
    KSTEP_H(pS0, pS1, o1, 1);    // k  32..63 : nf[src] 32..63
    KSTEP_H(pD0, pD1, o0, 2);    // k  64..95 : nf[dst] 0..31
    KSTEP_H(pD0, pD1, o1, 3);    // k  96..127: nf[dst] 32..63
    KSTEP_E(o0, 4, 0);           // k 128..159: ef 0..31  (+stash)
    KSTEP_E(o1, 5, 32);          // k 160..191: ef 32..63 (+stash)
#undef KSTEP_H
#undef KSTEP_E

    // bias + tanh GELU -> h_lds (bf16), certified C/D mapping
#pragma unroll
    for (int ct = 0; ct < 8; ++ct) {
        const int col = ct * 16 + lo;
        const float bb = b1[col];
#pragma unroll
        for (int rt = 0; rt < 2; ++rt)
#pragma unroll
            for (int r = 0; r < 4; ++r) {
                float x = acc[rt][ct][r] + bb;
                h_lds[wave * 32 + rt * 16 + hi * 4 + r][col] = f2bf(gelu_fast(x));
            }
    }
    // no barrier: all LDS traffic stays within this wave's 32-row stripe

    // ---- GEMM2: [32 x 128] @ [128 x 64] per wave, fragment-ordered B ----
    f32x4 acc2[2][4];
#pragma unroll
    for (int i = 0; i < 2; ++i)
#pragma unroll
        for (int j = 0; j < 4; ++j)
#pragma unroll
            for (int q = 0; q < 4; ++q) acc2[i][j][q] = 0.0f;
#pragma unroll
    for (int ks = 0; ks < 4; ++ks) {
        const int k0 = ks * 32 + hi * 8;
        s16x8 a0 = *(const s16x8*)&h_lds[wave * 32 + lo][k0];
        s16x8 a1 = *(const s16x8*)&h_lds[wave * 32 + 16 + lo][k0];
#pragma unroll
        for (int ct = 0; ct < 4; ++ct) {
            s16x8 b = *(const s16x8*)(w2f + ((ks * 4 + ct) << 9) + lane * 8);
            acc2[0][ct] = __builtin_amdgcn_mfma_f32_16x16x32_bf16(a0, b, acc2[0][ct], 0, 0, 0);
            acc2[1][ct] = __builtin_amdgcn_mfma_f32_16x16x32_bf16(a1, b, acc2[1][ct], 0, 0, 0);
        }
    }

    // write update u to LDS with the certified C/D mapping (alias h_lds as f32)
    float (*u_lds)[68] = (float (*)[68])h_lds;   // 128*68*4 = 34816 B, exact alias
#pragma unroll
    for (int ct = 0; ct < 4; ++ct)
#pragma unroll
        for (int rt = 0; rt < 2; ++rt)
#pragma unroll
            for (int r = 0; r < 4; ++r)
                u_lds[wave * 32 + rt * 16 + hi * 4 + r][ct * 16 + lo] = acc2[rt][ct][r];

    // ---- certified SERIAL epilogue: lane = output column ----
    const float b2v = b2[lane], gmv = gamma[lane], btv = beta[lane];
#pragma unroll 4
    for (int e = 0; e < 32; ++e) {
        const int er   = wave * 32 + e;              // block-local row
        const int erow = blockIdx.x * 128 + er;      // global edge row
        const float efv = u2f(((u32)(unsigned short)ef_lds[er][lane]) << 16);
        float o = u_lds[er][lane] + b2v + efv;
        float s = o, s2 = o * o;
#pragma unroll
        for (int m = 1; m < 64; m <<= 1) { s += __shfl_xor(s, m); s2 += __shfl_xor(s2, m); }
        const float mean = s * 0.015625f;
        const float var  = s2 * 0.015625f - mean * mean;
        const float rs   = rsqrtf(var + 1e-5f);
        const float out  = (o - mean) * rs * gmv + btv;
        eout[(size_t)erow * 64 + lane] = out;
        const int dn = ei[NE + erow];
        atomicAdd(&agg[(size_t)dn * 64 + lane], out);
        if (lane == 0) atomicAdd(&cnt[dn], 1.0f);
    }
}

// ---- node kernel: r11 certified form, verbatim ----
__global__ __launch_bounds__(256) void node_valu(
    const float* __restrict__ nf,
    const float* __restrict__ w1, const float* __restrict__ b1,
    const float* __restrict__ w2, const float* __restrict__ b2,
    const float* __restrict__ gamma, const float* __restrict__ beta,
    const float* __restrict__ agg, const float* __restrict__ cnt,
    float* __restrict__ nout)
{
    __shared__ float xs[4][128];
    __shared__ float hs[4][128];
    const int wave = threadIdx.x >> 6, lane = threadIdx.x & 63;
    const int n = blockIdx.x * 4 + wave;         // grid covers exactly NN
    if (n >= NN) return;                          // whole-wave exit; no barriers here

    const float ic = 1.0f / fmaxf(cnt[n], 1.0f);
    xs[wave][lane]      = nf[(size_t)n * 64 + lane];
    xs[wave][64 + lane] = agg[(size_t)n * 64 + lane] * ic;

    float a0 = b1[lane], a1 = b1[64 + lane];
#pragma unroll 8
    for (int k = 0; k < 128; ++k) {
        const float xv = xs[wave][k];            // LDS broadcast
        a0 += xv * w1[k * 128 + lane];
        a1 += xv * w1[k * 128 + 64 + lane];
    }
    hs[wave][lane]      = gelu_exact(a0);
    hs[wave][64 + lane] = gelu_exact(a1);

    float o = b2[lane];
#pragma unroll 8
    for (int k = 0; k < 128; ++k)
        o += hs[wave][k] * w2[k * 64 + lane];
    o += nf[(size_t)n * 64 + lane];              // residual

    float s = o, s2 = o * o;
#pragma unroll
    for (int m = 1; m < 64; m <<= 1) { s += __shfl_xor(s, m); s2 += __shfl_xor(s2, m); }
    const float mean = s * 0.015625f;
    const float var  = s2 * 0.015625f - mean * mean;
    const float rs   = rsqrtf(var + 1e-5f);
    nout[(size_t)n * 64 + lane] = (o - mean) * rs * gamma[lane] + beta[lane];
}

extern "C" void kernel_launch(void* const* d_in, const int* in_sizes, int n_in,
                              void* d_out, int out_size, void* d_ws, size_t ws_size,
                              hipStream_t stream)
{
    const float* nf  = (const float*)d_in[0];
    const int*   ei  = (const int*)d_in[1];
    const float* ef  = (const float*)d_in[2];
    const float* ew1 = (const float*)d_in[3];
    const float* eb1 = (const float*)d_in[4];
    const float* ew2 = (const float*)d_in[5];
    const float* eb2 = (const float*)d_in[6];
    const float* nw1 = (const float*)d_in[7];
    const float* nb1 = (const float*)d_in[8];
    const float* nw2 = (const float*)d_in[9];
    const float* nb2 = (const float*)d_in[10];
    const float* eg  = (const float*)d_in[11];
    const float* ebt = (const float*)d_in[12];
    const float* ng  = (const float*)d_in[13];
    const float* nbt = (const float*)d_in[14];

    float* node_out = (float*)d_out;
    float* edge_out = node_out + (size_t)NN * 64;
    char*  ws   = (char*)d_ws;
    float* cnt  = (float*)(ws);             // 200000 B
    short* w1f  = (short*)(ws + 200704);    // 49152 B
    short* w2f  = (short*)(ws + 249856);    // 16384 B
    short* nfh  = (short*)(ws + 266240);    // 6.4 MB
    float* agg  = node_out;                 // reuse node_out region as agg accumulator

    hipMemsetAsync(agg, 0, (size_t)NN * 64 * 4, stream);
    hipMemsetAsync(cnt, 0, (size_t)NN * 4, stream);
    prep_e<<<(NN * 64 + 255) / 256, 256, 0, stream>>>(nf, ew1, ew2, nfh, w1f, w2f);
    edge_k<<<NE / 128, 256, 0, stream>>>(nfh, ei, ef, w1f, eb1, w2f, eb2, eg, ebt,
                                         edge_out, agg, cnt);
    node_valu<<<NN / 4, 256, 0, stream>>>(nf, nw1, nb1, nw2, nb2, ng, nbt,
                                          agg, cnt, node_out);
}

// Round 15
// 492.913 us; speedup vs baseline: 1.1394x; 1.1394x over previous
//
#include <hip/hip_runtime.h>
#include <math.h>

#define NN 50000
#define NE 800000

typedef float f32x4 __attribute__((ext_vector_type(4)));
typedef short s16x8 __attribute__((ext_vector_type(8)));
typedef unsigned int u32;

__device__ __forceinline__ short f2bf(float f) {
    union { float f; u32 u; } v; v.f = f;
    u32 u = v.u;
    u += 0x7FFF + ((u >> 16) & 1);   // round-to-nearest-even
    return (short)(u >> 16);
}

__device__ __forceinline__ s16x8 cvt8(f32x4 a, f32x4 b) {
    s16x8 r;
    r[0] = f2bf(a[0]); r[1] = f2bf(a[1]); r[2] = f2bf(a[2]); r[3] = f2bf(a[3]);
    r[4] = f2bf(b[0]); r[5] = f2bf(b[1]); r[6] = f2bf(b[2]); r[7] = f2bf(b[3]);
    return r;
}

__device__ __forceinline__ float gelu_exact(float x) {
    return 0.5f * x * (1.0f + erff(x * 0.70710678118654752f));
}

// tanh-form GELU (certified r8)
__device__ __forceinline__ float gelu_fast(float x) {
    const float z = 1.5957691216f * x * (1.0f + 0.044715f * x * x);
    return x * __builtin_amdgcn_rcpf(1.0f + __expf(-z));
}

// ---- prep: nf->bf16 + fragment-ordered weights + zero agg/cnt (fused memsets) ----
__global__ __launch_bounds__(256) void prep_e(
    const float* __restrict__ nf, const float* __restrict__ ew1,
    const float* __restrict__ ew2,
    short* __restrict__ nfh, short* __restrict__ w1f, short* __restrict__ w2f,
    float* __restrict__ agg, float* __restrict__ cnt)
{
    int idx = blockIdx.x * 256 + threadIdx.x;
    if (idx < NN * 64) {
        nfh[idx] = f2bf(nf[idx]);
        agg[idx] = 0.0f;                     // fused memset (agg == node_out region)
    }
    if (idx < NN) cnt[idx] = 0.0f;           // fused memset
    if (idx < 24576) {                       // w1f: 6 ks * 8 ct * 512
        const int m = idx >> 9, r = idx & 511;
        const int lane = r >> 3, j = r & 7;
        const int ks = m >> 3, ct = m & 7;
        const int k = ks * 32 + (lane >> 4) * 8 + j;
        const int c = ct * 16 + (lane & 15);
        w1f[idx] = f2bf(ew1[k * 128 + c]);
    } else if (idx < 32768) {                // w2f: 4 ks * 4 ct * 512
        const int i = idx - 24576;
        const int m = i >> 9, r = i & 511;
        const int lane = r >> 3, j = r & 7;
        const int ks = m >> 2, ct = m & 3;
        const int k = ks * 32 + (lane >> 4) * 8 + j;
        const int c = ct * 16 + (lane & 15);
        w2f[i] = f2bf(ew2[k * 64 + c]);
    }
}

// ---- edge kernel: r13 certified dataflow, 1024-thread blocks, LDS-staged B ----
// 16 waves x 16 edges; w1f+w2f copied to LDS once per block (1 barrier), all
// B-fragment reads become ds_read_b128 -> ~28% fewer global tx per wave.
// LDS 135168 B -> 1 block/CU = 16 waves (~50% occ). ef residual read from
// global (L3-resident) instead of an LDS stash.
__global__ __launch_bounds__(1024) void edge_k(
    const short* __restrict__ nfh, const int* __restrict__ ei,
    const float* __restrict__ ef,
    const short* __restrict__ w1f, const float* __restrict__ b1,
    const short* __restrict__ w2f, const float* __restrict__ b2,
    const float* __restrict__ gamma, const float* __restrict__ beta,
    float* __restrict__ eout, float* __restrict__ agg, float* __restrict__ cnt)
{
    __shared__ short w1s[24576];             // 49152 B
    __shared__ short w2s[8192];              // 16384 B
    __shared__ short h_lds[256][136];        // 69632 B; aliased float[256][68]
    const int tid  = threadIdx.x;
    const int wave = tid >> 6, lane = tid & 63;
    const int lo = lane & 15, hi = lane >> 4;
    const int eb = blockIdx.x * 256 + wave * 16;

    // stage weight tables to LDS (16B/thread/iter), one barrier
    {
        s16x8* d1 = (s16x8*)w1s; const s16x8* s1 = (const s16x8*)w1f;
        d1[tid] = s1[tid]; d1[tid + 1024] = s1[tid + 1024]; d1[tid + 2048] = s1[tid + 2048];
        s16x8* d2 = (s16x8*)w2s; const s16x8* s2 = (const s16x8*)w2f;
        d2[tid] = s2[tid];
    }
    __syncthreads();

    const int ar0 = eb + lo;
    const int s0 = ei[ar0];
    const int d0 = ei[NE + ar0];

    const short* pS0 = nfh + (size_t)s0 * 64;
    const short* pD0 = nfh + (size_t)d0 * 64;
    const float* pE0 = ef + (size_t)ar0 * 64;
    const int o0 = hi * 8, o1 = 32 + hi * 8;

    f32x4 acc[8];
#pragma unroll
    for (int j = 0; j < 8; ++j)
#pragma unroll
        for (int q = 0; q < 4; ++q) acc[j][q] = 0.0f;

    // nf segments: bf16 gather; B fragments from LDS (lane*16B, full-BW pattern)
#define KSTEP_H(PTR, OFF, KS)                                                   \
    {                                                                           \
        s16x8 fa0 = *(const s16x8*)((PTR) + (OFF));                             \
        _Pragma("unroll")                                                       \
        for (int ct = 0; ct < 8; ++ct) {                                        \
            s16x8 b = *(const s16x8*)&w1s[(((KS) * 8 + ct) << 9) + lane * 8];   \
            acc[ct] = __builtin_amdgcn_mfma_f32_16x16x32_bf16(fa0, b, acc[ct], 0, 0, 0); \
        }                                                                       \
    }
#define KSTEP_E(OFF, KS)                                                        \
    {                                                                           \
        f32x4 x0l = *(const f32x4*)(pE0 + (OFF));                               \
        f32x4 x0h = *(const f32x4*)(pE0 + (OFF) + 4);                           \
        s16x8 fa0 = cvt8(x0l, x0h);                                             \
        _Pragma("unroll")                                                       \
        for (int ct = 0; ct < 8; ++ct) {                                        \
            s16x8 b = *(const s16x8*)&w1s[(((KS) * 8 + ct) << 9) + lane * 8];   \
            acc[ct] = __builtin_amdgcn_mfma_f32_16x16x32_bf16(fa0, b, acc[ct], 0, 0, 0); \
        }                                                                       \
    }

    KSTEP_H(pS0, o0, 0);      // k   0..31 : nf[src] 0..31
    KSTEP_H(pS0, o1, 1);      // k  32..63 : nf[src] 32..63
    KSTEP_H(pD0, o0, 2);      // k  64..95 : nf[dst] 0..31
    KSTEP_H(pD0, o1, 3);      // k  96..127: nf[dst] 32..63
    KSTEP_E(o0, 4);           // k 128..159: ef 0..31
    KSTEP_E(o1, 5);           // k 160..191: ef 32..63
#undef KSTEP_H
#undef KSTEP_E

    // bias + tanh GELU -> h_lds (bf16), certified C/D mapping
#pragma unroll
    for (int ct = 0; ct < 8; ++ct) {
        const int col = ct * 16 + lo;
        const float bb = b1[col];
#pragma unroll
        for (int r = 0; r < 4; ++r) {
            float x = acc[ct][r] + bb;
            h_lds[wave * 16 + hi * 4 + r][col] = f2bf(gelu_fast(x));
        }
    }
    // no barrier: all LDS traffic below stays within this wave's 16-row stripe

    // ---- GEMM2: [16 x 128] @ [128 x 64] per wave, B from LDS ----
    f32x4 acc2[4];
#pragma unroll
    for (int j = 0; j < 4; ++j)
#pragma unroll
        for (int q = 0; q < 4; ++q) acc2[j][q] = 0.0f;
#pragma unroll
    for (int ks = 0; ks < 4; ++ks) {
        const int k0 = ks * 32 + hi * 8;
        s16x8 a0 = *(const s16x8*)&h_lds[wave * 16 + lo][k0];
#pragma unroll
        for (int ct = 0; ct < 4; ++ct) {
            s16x8 b = *(const s16x8*)&w2s[((ks * 4 + ct) << 9) + lane * 8];
            acc2[ct] = __builtin_amdgcn_mfma_f32_16x16x32_bf16(a0, b, acc2[ct], 0, 0, 0);
        }
    }

    // write update u to LDS with the certified C/D mapping (alias h_lds as f32)
    float (*u_lds)[68] = (float (*)[68])h_lds;   // 256*68*4 = 69632 B, exact alias
#pragma unroll
    for (int ct = 0; ct < 4; ++ct)
#pragma unroll
        for (int r = 0; r < 4; ++r)
            u_lds[wave * 16 + hi * 4 + r][ct * 16 + lo] = acc2[ct][r];

    // ---- certified SERIAL epilogue: lane = output column; residual from ef ----
    const float b2v = b2[lane], gmv = gamma[lane], btv = beta[lane];
#pragma unroll 4
    for (int e = 0; e < 16; ++e) {
        const int er   = wave * 16 + e;              // block-local row
        const int erow = blockIdx.x * 256 + er;      // global edge row
        float o = u_lds[er][lane] + b2v + ef[(size_t)erow * 64 + lane];
        float s = o, s2 = o * o;
#pragma unroll
        for (int m = 1; m < 64; m <<= 1) { s += __shfl_xor(s, m); s2 += __shfl_xor(s2, m); }
        const float mean = s * 0.015625f;
        const float var  = s2 * 0.015625f - mean * mean;
        const float rs   = rsqrtf(var + 1e-5f);
        const float out  = (o - mean) * rs * gmv + btv;
        eout[(size_t)erow * 64 + lane] = out;
        const int dn = ei[NE + erow];
        atomicAdd(&agg[(size_t)dn * 64 + lane], out);
        if (lane == 0) atomicAdd(&cnt[dn], 1.0f);
    }
}

// ---- node kernel: certified form + ILP-split accumulators ----
__global__ __launch_bounds__(256) void node_valu(
    const float* __restrict__ nf,
    const float* __restrict__ w1, const float* __restrict__ b1,
    const float* __restrict__ w2, const float* __restrict__ b2,
    const float* __restrict__ gamma, const float* __restrict__ beta,
    const float* __restrict__ agg, const float* __restrict__ cnt,
    float* __restrict__ nout)
{
    __shared__ float xs[4][128];
    __shared__ float hs[4][128];
    const int wave = threadIdx.x >> 6, lane = threadIdx.x & 63;
    const int n = blockIdx.x * 4 + wave;         // grid covers exactly NN
    if (n >= NN) return;                          // whole-wave exit; no barriers here

    const float ic = 1.0f / fmaxf(cnt[n], 1.0f);
    xs[wave][lane]      = nf[(size_t)n * 64 + lane];
    xs[wave][64 + lane] = agg[(size_t)n * 64 + lane] * ic;

    float a0 = b1[lane], a1 = b1[64 + lane];
    float a0b = 0.f, a1b = 0.f;
#pragma unroll 8
    for (int k = 0; k < 128; k += 2) {
        const float xv0 = xs[wave][k], xv1 = xs[wave][k + 1];
        a0  += xv0 * w1[k * 128 + lane];
        a0b += xv1 * w1[(k + 1) * 128 + lane];
        a1  += xv0 * w1[k * 128 + 64 + lane];
        a1b += xv1 * w1[(k + 1) * 128 + 64 + lane];
    }
    hs[wave][lane]      = gelu_exact(a0 + a0b);
    hs[wave][64 + lane] = gelu_exact(a1 + a1b);

    float o = b2[lane], ob = 0.f;
#pragma unroll 8
    for (int k = 0; k < 128; k += 2) {
        o  += hs[wave][k] * w2[k * 64 + lane];
        ob += hs[wave][k + 1] * w2[(k + 1) * 64 + lane];
    }
    o += ob + nf[(size_t)n * 64 + lane];         // residual

    float s = o, s2 = o * o;
#pragma unroll
    for (int m = 1; m < 64; m <<= 1) { s += __shfl_xor(s, m); s2 += __shfl_xor(s2, m); }
    const float mean = s * 0.015625f;
    const float var  = s2 * 0.015625f - mean * mean;
    const float rs   = rsqrtf(var + 1e-5f);
    nout[(size_t)n * 64 + lane] = (o - mean) * rs * gamma[lane] + beta[lane];
}

extern "C" void kernel_launch(void* const* d_in, const int* in_sizes, int n_in,
                              void* d_out, int out_size, void* d_ws, size_t ws_size,
                              hipStream_t stream)
{
    const float* nf  = (const float*)d_in[0];
    const int*   ei  = (const int*)d_in[1];
    const float* ef  = (const float*)d_in[2];
    const float* ew1 = (const float*)d_in[3];
    const float* eb1 = (const float*)d_in[4];
    const float* ew2 = (const float*)d_in[5];
    const float* eb2 = (const float*)d_in[6];
    const float* nw1 = (const float*)d_in[7];
    const float* nb1 = (const float*)d_in[8];
    const float* nw2 = (const float*)d_in[9];
    const float* nb2 = (const float*)d_in[10];
    const float* eg  = (const float*)d_in[11];
    const float* ebt = (const float*)d_in[12];
    const float* ng  = (const float*)d_in[13];
    const float* nbt = (const float*)d_in[14];

    float* node_out = (float*)d_out;
    float* edge_out = node_out + (size_t)NN * 64;
    char*  ws   = (char*)d_ws;
    float* cnt  = (float*)(ws);             // 200000 B
    short* w1f  = (short*)(ws + 200704);    // 49152 B
    short* w2f  = (short*)(ws + 249856);    // 16384 B
    short* nfh  = (short*)(ws + 266240);    // 6.4 MB
    float* agg  = node_out;                 // reuse node_out region as agg accumulator

    prep_e<<<(NN * 64 + 255) / 256, 256, 0, stream>>>(nf, ew1, ew2, nfh, w1f, w2f,
                                                      agg, cnt);
    edge_k<<<NE / 256, 1024, 0, stream>>>(nfh, ei, ef, w1f, eb1, w2f, eb2, eg, ebt,
                                          edge_out, agg, cnt);
    node_valu<<<NN / 4, 256, 0, stream>>>(nf, nw1, nb1, nw2, nb2, ng, nbt,
                                          agg, cnt, node_out);
}

// Round 16
// 381.771 us; speedup vs baseline: 1.4711x; 1.2911x over previous
//
#include <hip/hip_runtime.h>
#include <math.h>

#define NN 50000
#define NE 800000

typedef float f32x4 __attribute__((ext_vector_type(4)));
typedef short s16x8 __attribute__((ext_vector_type(8)));
typedef unsigned int u32;

__device__ __forceinline__ short f2bf(float f) {
    union { float f; u32 u; } v; v.f = f;
    u32 u = v.u;
    u += 0x7FFF + ((u >> 16) & 1);   // round-to-nearest-even
    return (short)(u >> 16);
}

__device__ __forceinline__ s16x8 cvt8(f32x4 a, f32x4 b) {
    s16x8 r;
    r[0] = f2bf(a[0]); r[1] = f2bf(a[1]); r[2] = f2bf(a[2]); r[3] = f2bf(a[3]);
    r[4] = f2bf(b[0]); r[5] = f2bf(b[1]); r[6] = f2bf(b[2]); r[7] = f2bf(b[3]);
    return r;
}

__device__ __forceinline__ s16x8 cvt8s(f32x4 a, f32x4 b, float sc) {
    s16x8 r;
    r[0] = f2bf(a[0] * sc); r[1] = f2bf(a[1] * sc); r[2] = f2bf(a[2] * sc); r[3] = f2bf(a[3] * sc);
    r[4] = f2bf(b[0] * sc); r[5] = f2bf(b[1] * sc); r[6] = f2bf(b[2] * sc); r[7] = f2bf(b[3] * sc);
    return r;
}

// tanh-form GELU (certified r8)
__device__ __forceinline__ float gelu_fast(float x) {
    const float z = 1.5957691216f * x * (1.0f + 0.044715f * x * x);
    return x * __builtin_amdgcn_rcpf(1.0f + __expf(-z));
}

// ---- prep: nf->bf16, ALL weights fragment-ordered, zero agg/cnt ----
__global__ __launch_bounds__(256) void prep_e(
    const float* __restrict__ nf, const float* __restrict__ ew1,
    const float* __restrict__ ew2, const float* __restrict__ nw1,
    const float* __restrict__ nw2,
    short* __restrict__ nfh, short* __restrict__ w1f, short* __restrict__ w2f,
    short* __restrict__ w1nf, short* __restrict__ w2nf,
    float* __restrict__ agg, float* __restrict__ cnt)
{
    int idx = blockIdx.x * 256 + threadIdx.x;
    if (idx < NN * 64) {
        nfh[idx] = f2bf(nf[idx]);
        agg[idx] = 0.0f;                     // fused memset (agg == node_out region)
    }
    if (idx < NN) cnt[idx] = 0.0f;           // fused memset
    if (idx < 24576) {                       // e_w1 frag: 6 ks * 8 ct * 512
        const int m = idx >> 9, r = idx & 511;
        const int lane = r >> 3, j = r & 7;
        const int ks = m >> 3, ct = m & 7;
        const int k = ks * 32 + (lane >> 4) * 8 + j;
        const int c = ct * 16 + (lane & 15);
        w1f[idx] = f2bf(ew1[k * 128 + c]);
    } else if (idx < 32768) {                // e_w2 frag: 4 ks * 4 ct * 512
        const int i = idx - 24576;
        const int m = i >> 9, r = i & 511;
        const int lane = r >> 3, j = r & 7;
        const int ks = m >> 2, ct = m & 3;
        const int k = ks * 32 + (lane >> 4) * 8 + j;
        const int c = ct * 16 + (lane & 15);
        w2f[i] = f2bf(ew2[k * 64 + c]);
    } else if (idx < 49152) {                // n_w1 frag: 4 ks * 8 ct * 512
        const int i = idx - 32768;
        const int m = i >> 9, r = i & 511;
        const int lane = r >> 3, j = r & 7;
        const int ks = m >> 3, ct = m & 7;
        const int k = ks * 32 + (lane >> 4) * 8 + j;
        const int c = ct * 16 + (lane & 15);
        w1nf[i] = f2bf(nw1[k * 128 + c]);
    } else if (idx < 57344) {                // n_w2 frag: 4 ks * 4 ct * 512
        const int i = idx - 49152;
        const int m = i >> 9, r = i & 511;
        const int lane = r >> 3, j = r & 7;
        const int ks = m >> 2, ct = m & 3;
        const int k = ks * 32 + (lane >> 4) * 8 + j;
        const int c = ct * 16 + (lane & 15);
        w2nf[i] = f2bf(nw2[k * 64 + c]);
    }
}

// ---- edge kernel: r15 certified, byte-identical ----
__global__ __launch_bounds__(1024) void edge_k(
    const short* __restrict__ nfh, const int* __restrict__ ei,
    const float* __restrict__ ef,
    const short* __restrict__ w1f, const float* __restrict__ b1,
    const short* __restrict__ w2f, const float* __restrict__ b2,
    const float* __restrict__ gamma, const float* __restrict__ beta,
    float* __restrict__ eout, float* __restrict__ agg, float* __restrict__ cnt)
{
    __shared__ short w1s[24576];             // 49152 B
    __shared__ short w2s[8192];              // 16384 B
    __shared__ short h_lds[256][136];        // 69632 B; aliased float[256][68]
    const int tid  = threadIdx.x;
    const int wave = tid >> 6, lane = tid & 63;
    const int lo = lane & 15, hi = lane >> 4;
    const int eb = blockIdx.x * 256 + wave * 16;

    {
        s16x8* d1 = (s16x8*)w1s; const s16x8* s1 = (const s16x8*)w1f;
        d1[tid] = s1[tid]; d1[tid + 1024] = s1[tid + 1024]; d1[tid + 2048] = s1[tid + 2048];
        s16x8* d2 = (s16x8*)w2s; const s16x8* s2 = (const s16x8*)w2f;
        d2[tid] = s2[tid];
    }
    __syncthreads();

    const int ar0 = eb + lo;
    const int s0 = ei[ar0];
    const int d0 = ei[NE + ar0];

    const short* pS0 = nfh + (size_t)s0 * 64;
    const short* pD0 = nfh + (size_t)d0 * 64;
    const float* pE0 = ef + (size_t)ar0 * 64;
    const int o0 = hi * 8, o1 = 32 + hi * 8;

    f32x4 acc[8];
#pragma unroll
    for (int j = 0; j < 8; ++j)
#pragma unroll
        for (int q = 0; q < 4; ++q) acc[j][q] = 0.0f;

#define KSTEP_H(PTR, OFF, KS)                                                   \
    {                                                                           \
        s16x8 fa0 = *(const s16x8*)((PTR) + (OFF));                             \
        _Pragma("unroll")                                                       \
        for (int ct = 0; ct < 8; ++ct) {                                        \
            s16x8 b = *(const s16x8*)&w1s[(((KS) * 8 + ct) << 9) + lane * 8];   \
            acc[ct] = __builtin_amdgcn_mfma_f32_16x16x32_bf16(fa0, b, acc[ct], 0, 0, 0); \
        }                                                                       \
    }
#define KSTEP_E(OFF, KS)                                                        \
    {                                                                           \
        f32x4 x0l = *(const f32x4*)(pE0 + (OFF));                               \
        f32x4 x0h = *(const f32x4*)(pE0 + (OFF) + 4);                           \
        s16x8 fa0 = cvt8(x0l, x0h);                                             \
        _Pragma("unroll")                                                       \
        for (int ct = 0; ct < 8; ++ct) {                                        \
            s16x8 b = *(const s16x8*)&w1s[(((KS) * 8 + ct) << 9) + lane * 8];   \
            acc[ct] = __builtin_amdgcn_mfma_f32_16x16x32_bf16(fa0, b, acc[ct], 0, 0, 0); \
        }                                                                       \
    }

    KSTEP_H(pS0, o0, 0);      // k   0..31 : nf[src] 0..31
    KSTEP_H(pS0, o1, 1);      // k  32..63 : nf[src] 32..63
    KSTEP_H(pD0, o0, 2);      // k  64..95 : nf[dst] 0..31
    KSTEP_H(pD0, o1, 3);      // k  96..127: nf[dst] 32..63
    KSTEP_E(o0, 4);           // k 128..159: ef 0..31
    KSTEP_E(o1, 5);           // k 160..191: ef 32..63
#undef KSTEP_H
#undef KSTEP_E

    // bias + tanh GELU -> h_lds (bf16), certified C/D mapping
#pragma unroll
    for (int ct = 0; ct < 8; ++ct) {
        const int col = ct * 16 + lo;
        const float bb = b1[col];
#pragma unroll
        for (int r = 0; r < 4; ++r) {
            float x = acc[ct][r] + bb;
            h_lds[wave * 16 + hi * 4 + r][col] = f2bf(gelu_fast(x));
        }
    }
    // no barrier: all LDS traffic below stays within this wave's 16-row stripe

    f32x4 acc2[4];
#pragma unroll
    for (int j = 0; j < 4; ++j)
#pragma unroll
        for (int q = 0; q < 4; ++q) acc2[j][q] = 0.0f;
#pragma unroll
    for (int ks = 0; ks < 4; ++ks) {
        const int k0 = ks * 32 + hi * 8;
        s16x8 a0 = *(const s16x8*)&h_lds[wave * 16 + lo][k0];
#pragma unroll
        for (int ct = 0; ct < 4; ++ct) {
            s16x8 b = *(const s16x8*)&w2s[((ks * 4 + ct) << 9) + lane * 8];
            acc2[ct] = __builtin_amdgcn_mfma_f32_16x16x32_bf16(a0, b, acc2[ct], 0, 0, 0);
        }
    }

    float (*u_lds)[68] = (float (*)[68])h_lds;   // 256*68*4 = 69632 B, exact alias
#pragma unroll
    for (int ct = 0; ct < 4; ++ct)
#pragma unroll
        for (int r = 0; r < 4; ++r)
            u_lds[wave * 16 + hi * 4 + r][ct * 16 + lo] = acc2[ct][r];

    const float b2v = b2[lane], gmv = gamma[lane], btv = beta[lane];
#pragma unroll 4
    for (int e = 0; e < 16; ++e) {
        const int er   = wave * 16 + e;              // block-local row
        const int erow = blockIdx.x * 256 + er;      // global edge row
        float o = u_lds[er][lane] + b2v + ef[(size_t)erow * 64 + lane];
        float s = o, s2 = o * o;
#pragma unroll
        for (int m = 1; m < 64; m <<= 1) { s += __shfl_xor(s, m); s2 += __shfl_xor(s2, m); }
        const float mean = s * 0.015625f;
        const float var  = s2 * 0.015625f - mean * mean;
        const float rs   = rsqrtf(var + 1e-5f);
        const float out  = (o - mean) * rs * gmv + btv;
        eout[(size_t)erow * 64 + lane] = out;
        const int dn = ei[NE + erow];
        atomicAdd(&agg[(size_t)dn * 64 + lane], out);
        if (lane == 0) atomicAdd(&cnt[dn], 1.0f);
    }
}

// ---- node kernel: MFMA port of the certified template (no gather, no atomics) ----
// 256 threads = 4 waves x 16 nodes; n-weights staged to LDS; A = nfh (bf16)
// + agg*(1/cnt) scaled-cvt; tail blocks: loads clamped, stores guarded.
__global__ __launch_bounds__(256) void node_k(
    const short* __restrict__ nfh, const float* __restrict__ nf,
    const float* __restrict__ agg, const float* __restrict__ cnt,
    const short* __restrict__ w1nf, const float* __restrict__ b1,
    const short* __restrict__ w2nf, const float* __restrict__ b2,
    const float* __restrict__ gamma, const float* __restrict__ beta,
    float* __restrict__ nout)
{
    __shared__ short w1s[16384];             // 32768 B
    __shared__ short w2s[8192];              // 16384 B
    __shared__ short h_lds[64][136];         // 17408 B -> total 66560 B, 2 blocks/CU
    const int tid  = threadIdx.x;
    const int wave = tid >> 6, lane = tid & 63;
    const int lo = lane & 15, hi = lane >> 4;

    {
        s16x8* d1 = (s16x8*)w1s; const s16x8* s1 = (const s16x8*)w1nf;
#pragma unroll
        for (int k = 0; k < 8; ++k) d1[tid + k * 256] = s1[tid + k * 256];
        s16x8* d2 = (s16x8*)w2s; const s16x8* s2 = (const s16x8*)w2nf;
#pragma unroll
        for (int k = 0; k < 4; ++k) d2[tid + k * 256] = s2[tid + k * 256];
    }
    __syncthreads();

    const int nr = blockIdx.x * 64 + wave * 16 + lo;
    const int cr = min(nr, NN - 1);
    const float ic = 1.0f / fmaxf(cnt[cr], 1.0f);
    const short* pN = nfh + (size_t)cr * 64;
    const float* pA = agg + (size_t)cr * 64;
    const int o0 = hi * 8, o1 = 32 + hi * 8;

    f32x4 acc[8];
#pragma unroll
    for (int j = 0; j < 8; ++j)
#pragma unroll
        for (int q = 0; q < 4; ++q) acc[j][q] = 0.0f;

#define NK_H(OFF, KS)                                                           \
    {                                                                           \
        s16x8 fa0 = *(const s16x8*)(pN + (OFF));                                \
        _Pragma("unroll")                                                       \
        for (int ct = 0; ct < 8; ++ct) {                                        \
            s16x8 b = *(const s16x8*)&w1s[(((KS) * 8 + ct) << 9) + lane * 8];   \
            acc[ct] = __builtin_amdgcn_mfma_f32_16x16x32_bf16(fa0, b, acc[ct], 0, 0, 0); \
        }                                                                       \
    }
#define NK_A(OFF, KS)                                                           \
    {                                                                           \
        f32x4 xl = *(const f32x4*)(pA + (OFF));                                 \
        f32x4 xh = *(const f32x4*)(pA + (OFF) + 4);                             \
        s16x8 fa0 = cvt8s(xl, xh, ic);                                          \
        _Pragma("unroll")                                                       \
        for (int ct = 0; ct < 8; ++ct) {                                        \
            s16x8 b = *(const s16x8*)&w1s[(((KS) * 8 + ct) << 9) + lane * 8];   \
            acc[ct] = __builtin_amdgcn_mfma_f32_16x16x32_bf16(fa0, b, acc[ct], 0, 0, 0); \
        }                                                                       \
    }

    NK_H(o0, 0);              // k  0..31 : nf 0..31
    NK_H(o1, 1);              // k 32..63 : nf 32..63
    NK_A(o0, 2);              // k 64..95 : agg/cnt 0..31
    NK_A(o1, 3);              // k 96..127: agg/cnt 32..63
#undef NK_H
#undef NK_A

    // bias + tanh GELU -> h_lds (bf16), certified C/D mapping
#pragma unroll
    for (int ct = 0; ct < 8; ++ct) {
        const int col = ct * 16 + lo;
        const float bb = b1[col];
#pragma unroll
        for (int r = 0; r < 4; ++r) {
            float x = acc[ct][r] + bb;
            h_lds[wave * 16 + hi * 4 + r][col] = f2bf(gelu_fast(x));
        }
    }
    // no barrier: all LDS traffic below stays within this wave's 16-row stripe

    f32x4 acc2[4];
#pragma unroll
    for (int j = 0; j < 4; ++j)
#pragma unroll
        for (int q = 0; q < 4; ++q) acc2[j][q] = 0.0f;
#pragma unroll
    for (int ks = 0; ks < 4; ++ks) {
        const int k0 = ks * 32 + hi * 8;
        s16x8 a0 = *(const s16x8*)&h_lds[wave * 16 + lo][k0];
#pragma unroll
        for (int ct = 0; ct < 4; ++ct) {
            s16x8 b = *(const s16x8*)&w2s[((ks * 4 + ct) << 9) + lane * 8];
            acc2[ct] = __builtin_amdgcn_mfma_f32_16x16x32_bf16(a0, b, acc2[ct], 0, 0, 0);
        }
    }

    float (*u_lds)[68] = (float (*)[68])h_lds;   // 64*68*4 = 17408 B, exact alias
#pragma unroll
    for (int ct = 0; ct < 4; ++ct)
#pragma unroll
        for (int r = 0; r < 4; ++r)
            u_lds[wave * 16 + hi * 4 + r][ct * 16 + lo] = acc2[ct][r];

    // certified SERIAL epilogue: lane = output column; residual from nf (f32)
    const float b2v = b2[lane], gmv = gamma[lane], btv = beta[lane];
#pragma unroll 4
    for (int e = 0; e < 16; ++e) {
        const int er   = wave * 16 + e;
        const int nrow = blockIdx.x * 64 + er;
        if (nrow < NN) {                             // wave-uniform guard
            float o = u_lds[er][lane] + b2v + nf[(size_t)nrow * 64 + lane];
            float s = o, s2 = o * o;
#pragma unroll
            for (int m = 1; m < 64; m <<= 1) { s += __shfl_xor(s, m); s2 += __shfl_xor(s2, m); }
            const float mean = s * 0.015625f;
            const float var  = s2 * 0.015625f - mean * mean;
            const float rs   = rsqrtf(var + 1e-5f);
            nout[(size_t)nrow * 64 + lane] = (o - mean) * rs * gmv + btv;
        }
    }
}

extern "C" void kernel_launch(void* const* d_in, const int* in_sizes, int n_in,
                              void* d_out, int out_size, void* d_ws, size_t ws_size,
                              hipStream_t stream)
{
    const float* nf  = (const float*)d_in[0];
    const int*   ei  = (const int*)d_in[1];
    const float* ef  = (const float*)d_in[2];
    const float* ew1 = (const float*)d_in[3];
    const float* eb1 = (const float*)d_in[4];
    const float* ew2 = (const float*)d_in[5];
    const float* eb2 = (const float*)d_in[6];
    const float* nw1 = (const float*)d_in[7];
    const float* nb1 = (const float*)d_in[8];
    const float* nw2 = (const float*)d_in[9];
    const float* nb2 = (const float*)d_in[10];
    const float* eg  = (const float*)d_in[11];
    const float* ebt = (const float*)d_in[12];
    const float* ng  = (const float*)d_in[13];
    const float* nbt = (const float*)d_in[14];

    float* node_out = (float*)d_out;
    float* edge_out = node_out + (size_t)NN * 64;
    char*  ws    = (char*)d_ws;
    float* cnt   = (float*)(ws);             // 200000 B (pad to 200704)
    short* w1f   = (short*)(ws + 200704);    // 49152 B -> 249856
    short* w2f   = (short*)(ws + 249856);    // 16384 B -> 266240
    short* w1nf  = (short*)(ws + 266240);    // 32768 B -> 299008
    short* w2nf  = (short*)(ws + 299008);    // 16384 B -> 315392
    short* nfh   = (short*)(ws + 315392);    // 6.4 MB  -> 6,715,392
    float* agg   = node_out;                 // reuse node_out region as agg accumulator

    prep_e<<<(NN * 64 + 255) / 256, 256, 0, stream>>>(nf, ew1, ew2, nw1, nw2,
                                                      nfh, w1f, w2f, w1nf, w2nf,
                                                      agg, cnt);
    edge_k<<<NE / 256, 1024, 0, stream>>>(nfh, ei, ef, w1f, eb1, w2f, eb2, eg, ebt,
                                          edge_out, agg, cnt);
    node_k<<<(NN + 63) / 64, 256, 0, stream>>>(nfh, nf, agg, cnt, w1nf, nb1,
                                               w2nf, nb2, ng, nbt, node_out);
}

// Round 17
// 336.739 us; speedup vs baseline: 1.6678x; 1.1337x over previous
//
#include <hip/hip_runtime.h>
#include <math.h>

#define NN 50000
#define NE 800000

typedef float f32x4 __attribute__((ext_vector_type(4)));
typedef short s16x8 __attribute__((ext_vector_type(8)));
typedef short s16x2 __attribute__((ext_vector_type(2)));
typedef unsigned int u32;

__device__ __forceinline__ short f2bf(float f) {
    union { float f; u32 u; } v; v.f = f;
    u32 u = v.u;
    u += 0x7FFF + ((u >> 16) & 1);   // round-to-nearest-even
    return (short)(u >> 16);
}

__device__ __forceinline__ float u2f(u32 u) {
    union { u32 u; float f; } v; v.u = u; return v.f;
}

__device__ __forceinline__ s16x8 cvt8(f32x4 a, f32x4 b) {
    s16x8 r;
    r[0] = f2bf(a[0]); r[1] = f2bf(a[1]); r[2] = f2bf(a[2]); r[3] = f2bf(a[3]);
    r[4] = f2bf(b[0]); r[5] = f2bf(b[1]); r[6] = f2bf(b[2]); r[7] = f2bf(b[3]);
    return r;
}

// tanh-form GELU (certified r8)
__device__ __forceinline__ float gelu_fast(float x) {
    const float z = 1.5957691216f * x * (1.0f + 0.044715f * x * x);
    return x * __builtin_amdgcn_rcpf(1.0f + __expf(-z));
}

// packed bf16 atomic add (gfx90a+ global_atomic_pk_add_bf16)
__device__ __forceinline__ void agg_pk_add(short* p, short vlo, short vhi) {
    s16x2 d; d[0] = vlo; d[1] = vhi;
#if __has_builtin(__builtin_amdgcn_global_atomic_fadd_v2bf16)
    __builtin_amdgcn_global_atomic_fadd_v2bf16(
        (__attribute__((address_space(1))) s16x2*)(unsigned long long)p, d);
#else
    u32* p32 = (u32*)p;
    u32 old = *(volatile u32*)p32, assumed;
    do {
        assumed = old;
        float lo = u2f(((u32)(unsigned short)(assumed & 0xFFFF)) << 16) +
                   u2f(((u32)(unsigned short)vlo) << 16);
        float hi = u2f(assumed & 0xFFFF0000u) +
                   u2f(((u32)(unsigned short)vhi) << 16);
        u32 nw = ((u32)(unsigned short)f2bf(lo)) | (((u32)(unsigned short)f2bf(hi)) << 16);
        old = atomicCAS(p32, assumed, nw);
    } while (old != assumed);
#endif
}

// ---- prep: nf->bf16, fragment-ordered weights, zero aggh/cnt ----
__global__ __launch_bounds__(256) void prep_e(
    const float* __restrict__ nf, const float* __restrict__ ew1,
    const float* __restrict__ ew2, const float* __restrict__ nw1,
    const float* __restrict__ nw2,
    short* __restrict__ nfh, short* __restrict__ w1f, short* __restrict__ w2f,
    short* __restrict__ w1nf, short* __restrict__ w2nf,
    short* __restrict__ aggh, float* __restrict__ cnt)
{
    int idx = blockIdx.x * 256 + threadIdx.x;
    if (idx < NN * 64) {
        nfh[idx]  = f2bf(nf[idx]);
        aggh[idx] = 0;                       // fused memset (bf16 zero)
    }
    if (idx < NN) cnt[idx] = 0.0f;           // fused memset
    if (idx < 24576) {                       // e_w1 frag: 6 ks * 8 ct * 512
        const int m = idx >> 9, r = idx & 511;
        const int lane = r >> 3, j = r & 7;
        const int ks = m >> 3, ct = m & 7;
        const int k = ks * 32 + (lane >> 4) * 8 + j;
        const int c = ct * 16 + (lane & 15);
        w1f[idx] = f2bf(ew1[k * 128 + c]);
    } else if (idx < 32768) {                // e_w2 frag: 4 ks * 4 ct * 512
        const int i = idx - 24576;
        const int m = i >> 9, r = i & 511;
        const int lane = r >> 3, j = r & 7;
        const int ks = m >> 2, ct = m & 3;
        const int k = ks * 32 + (lane >> 4) * 8 + j;
        const int c = ct * 16 + (lane & 15);
        w2f[i] = f2bf(ew2[k * 64 + c]);
    } else if (idx < 49152) {                // n_w1 frag: 4 ks * 8 ct * 512
        const int i = idx - 32768;
        const int m = i >> 9, r = i & 511;
        const int lane = r >> 3, j = r & 7;
        const int ks = m >> 3, ct = m & 7;
        const int k = ks * 32 + (lane >> 4) * 8 + j;
        const int c = ct * 16 + (lane & 15);
        w1nf[i] = f2bf(nw1[k * 128 + c]);
    } else if (idx < 57344) {                // n_w2 frag: 4 ks * 4 ct * 512
        const int i = idx - 49152;
        const int m = i >> 9, r = i & 511;
        const int lane = r >> 3, j = r & 7;
        const int ks = m >> 2, ct = m & 3;
        const int k = ks * 32 + (lane >> 4) * 8 + j;
        const int c = ct * 16 + (lane & 15);
        w2nf[i] = f2bf(nw2[k * 64 + c]);
    }
}

// ---- edge kernel: r16 certified; ONLY delta = packed-bf16 agg atomics ----
__global__ __launch_bounds__(1024) void edge_k(
    const short* __restrict__ nfh, const int* __restrict__ ei,
    const float* __restrict__ ef,
    const short* __restrict__ w1f, const float* __restrict__ b1,
    const short* __restrict__ w2f, const float* __restrict__ b2,
    const float* __restrict__ gamma, const float* __restrict__ beta,
    float* __restrict__ eout, short* __restrict__ aggh, float* __restrict__ cnt)
{
    __shared__ short w1s[24576];             // 49152 B
    __shared__ short w2s[8192];              // 16384 B
    __shared__ short h_lds[256][136];        // 69632 B; aliased float[256][68]
    const int tid  = threadIdx.x;
    const int wave = tid >> 6, lane = tid & 63;
    const int lo = lane & 15, hi = lane >> 4;
    const int eb = blockIdx.x * 256 + wave * 16;

    {
        s16x8* d1 = (s16x8*)w1s; const s16x8* s1 = (const s16x8*)w1f;
        d1[tid] = s1[tid]; d1[tid + 1024] = s1[tid + 1024]; d1[tid + 2048] = s1[tid + 2048];
        s16x8* d2 = (s16x8*)w2s; const s16x8* s2 = (const s16x8*)w2f;
        d2[tid] = s2[tid];
    }
    __syncthreads();

    const int ar0 = eb + lo;
    const int s0 = ei[ar0];
    const int d0 = ei[NE + ar0];

    const short* pS0 = nfh + (size_t)s0 * 64;
    const short* pD0 = nfh + (size_t)d0 * 64;
    const float* pE0 = ef + (size_t)ar0 * 64;
    const int o0 = hi * 8, o1 = 32 + hi * 8;

    f32x4 acc[8];
#pragma unroll
    for (int j = 0; j < 8; ++j)
#pragma unroll
        for (int q = 0; q < 4; ++q) acc[j][q] = 0.0f;

#define KSTEP_H(PTR, OFF, KS)                                                   \
    {                                                                           \
        s16x8 fa0 = *(const s16x8*)((PTR) + (OFF));                             \
        _Pragma("unroll")                                                       \
        for (int ct = 0; ct < 8; ++ct) {                                        \
            s16x8 b = *(const s16x8*)&w1s[(((KS) * 8 + ct) << 9) + lane * 8];   \
            acc[ct] = __builtin_amdgcn_mfma_f32_16x16x32_bf16(fa0, b, acc[ct], 0, 0, 0); \
        }                                                                       \
    }
#define KSTEP_E(OFF, KS)                                                        \
    {                                                                           \
        f32x4 x0l = *(const f32x4*)(pE0 + (OFF));                               \
        f32x4 x0h = *(const f32x4*)(pE0 + (OFF) + 4);                           \
        s16x8 fa0 = cvt8(x0l, x0h);                                             \
        _Pragma("unroll")                                                       \
        for (int ct = 0; ct < 8; ++ct) {                                        \
            s16x8 b = *(const s16x8*)&w1s[(((KS) * 8 + ct) << 9) + lane * 8];   \
            acc[ct] = __builtin_amdgcn_mfma_f32_16x16x32_bf16(fa0, b, acc[ct], 0, 0, 0); \
        }                                                                       \
    }

    KSTEP_H(pS0, o0, 0);      // k   0..31 : nf[src] 0..31
    KSTEP_H(pS0, o1, 1);      // k  32..63 : nf[src] 32..63
    KSTEP_H(pD0, o0, 2);      // k  64..95 : nf[dst] 0..31
    KSTEP_H(pD0, o1, 3);      // k  96..127: nf[dst] 32..63
    KSTEP_E(o0, 4);           // k 128..159: ef 0..31
    KSTEP_E(o1, 5);           // k 160..191: ef 32..63
#undef KSTEP_H
#undef KSTEP_E

    // bias + tanh GELU -> h_lds (bf16), certified C/D mapping
#pragma unroll
    for (int ct = 0; ct < 8; ++ct) {
        const int col = ct * 16 + lo;
        const float bb = b1[col];
#pragma unroll
        for (int r = 0; r < 4; ++r) {
            float x = acc[ct][r] + bb;
            h_lds[wave * 16 + hi * 4 + r][col] = f2bf(gelu_fast(x));
        }
    }
    // no barrier: all LDS traffic below stays within this wave's 16-row stripe

    f32x4 acc2[4];
#pragma unroll
    for (int j = 0; j < 4; ++j)
#pragma unroll
        for (int q = 0; q < 4; ++q) acc2[j][q] = 0.0f;
#pragma unroll
    for (int ks = 0; ks < 4; ++ks) {
        const int k0 = ks * 32 + hi * 8;
        s16x8 a0 = *(const s16x8*)&h_lds[wave * 16 + lo][k0];
#pragma unroll
        for (int ct = 0; ct < 4; ++ct) {
            s16x8 b = *(const s16x8*)&w2s[((ks * 4 + ct) << 9) + lane * 8];
            acc2[ct] = __builtin_amdgcn_mfma_f32_16x16x32_bf16(a0, b, acc2[ct], 0, 0, 0);
        }
    }

    float (*u_lds)[68] = (float (*)[68])h_lds;   // 256*68*4 = 69632 B, exact alias
#pragma unroll
    for (int ct = 0; ct < 4; ++ct)
#pragma unroll
        for (int r = 0; r < 4; ++r)
            u_lds[wave * 16 + hi * 4 + r][ct * 16 + lo] = acc2[ct][r];

    const float b2v = b2[lane], gmv = gamma[lane], btv = beta[lane];
#pragma unroll 4
    for (int e = 0; e < 16; ++e) {
        const int er   = wave * 16 + e;              // block-local row
        const int erow = blockIdx.x * 256 + er;      // global edge row
        float o = u_lds[er][lane] + b2v + ef[(size_t)erow * 64 + lane];
        float s = o, s2 = o * o;
#pragma unroll
        for (int m = 1; m < 64; m <<= 1) { s += __shfl_xor(s, m); s2 += __shfl_xor(s2, m); }
        const float mean = s * 0.015625f;
        const float var  = s2 * 0.015625f - mean * mean;
        const float rs   = rsqrtf(var + 1e-5f);
        const float out  = (o - mean) * rs * gmv + btv;
        eout[(size_t)erow * 64 + lane] = out;
        const int dn = ei[NE + erow];
        const float nbv = __shfl_xor(out, 1);        // neighbor column's value
        if (!(lane & 1))                              // even lanes: packed pair
            agg_pk_add(&aggh[(size_t)dn * 64 + lane], f2bf(out), f2bf(nbv));
        if (lane == 0) atomicAdd(&cnt[dn], 1.0f);
    }
}

// ---- node kernel: r16 certified MFMA template; agg now bf16 ----
__global__ __launch_bounds__(256) void node_k(
    const short* __restrict__ nfh, const float* __restrict__ nf,
    const short* __restrict__ aggh, const float* __restrict__ cnt,
    const short* __restrict__ w1nf, const float* __restrict__ b1,
    const short* __restrict__ w2nf, const float* __restrict__ b2,
    const float* __restrict__ gamma, const float* __restrict__ beta,
    float* __restrict__ nout)
{
    __shared__ short w1s[16384];             // 32768 B
    __shared__ short w2s[8192];              // 16384 B
    __shared__ short h_lds[64][136];         // 17408 B -> total 66560 B
    const int tid  = threadIdx.x;
    const int wave = tid >> 6, lane = tid & 63;
    const int lo = lane & 15, hi = lane >> 4;

    {
        s16x8* d1 = (s16x8*)w1s; const s16x8* s1 = (const s16x8*)w1nf;
#pragma unroll
        for (int k = 0; k < 8; ++k) d1[tid + k * 256] = s1[tid + k * 256];
        s16x8* d2 = (s16x8*)w2s; const s16x8* s2 = (const s16x8*)w2nf;
#pragma unroll
        for (int k = 0; k < 4; ++k) d2[tid + k * 256] = s2[tid + k * 256];
    }
    __syncthreads();

    const int nr = blockIdx.x * 64 + wave * 16 + lo;
    const int cr = min(nr, NN - 1);
    const float ic = 1.0f / fmaxf(cnt[cr], 1.0f);
    const short* pN = nfh  + (size_t)cr * 64;
    const short* pA = aggh + (size_t)cr * 64;
    const int o0 = hi * 8, o1 = 32 + hi * 8;

    f32x4 acc[8];
#pragma unroll
    for (int j = 0; j < 8; ++j)
#pragma unroll
        for (int q = 0; q < 4; ++q) acc[j][q] = 0.0f;

#define NK_H(OFF, KS)                                                           \
    {                                                                           \
        s16x8 fa0 = *(const s16x8*)(pN + (OFF));                                \
        _Pragma("unroll")                                                       \
        for (int ct = 0; ct < 8; ++ct) {                                        \
            s16x8 b = *(const s16x8*)&w1s[(((KS) * 8 + ct) << 9) + lane * 8];   \
            acc[ct] = __builtin_amdgcn_mfma_f32_16x16x32_bf16(fa0, b, acc[ct], 0, 0, 0); \
        }                                                                       \
    }
#define NK_A(OFF, KS)                                                           \
    {                                                                           \
        s16x8 rw = *(const s16x8*)(pA + (OFF));                                 \
        s16x8 fa0;                                                              \
        _Pragma("unroll")                                                       \
        for (int j = 0; j < 8; ++j)                                             \
            fa0[j] = f2bf(u2f(((u32)(unsigned short)rw[j]) << 16) * ic);        \
        _Pragma("unroll")                                                       \
        for (int ct = 0; ct < 8; ++ct) {                                        \
            s16x8 b = *(const s16x8*)&w1s[(((KS) * 8 + ct) << 9) + lane * 8];   \
            acc[ct] = __builtin_amdgcn_mfma_f32_16x16x32_bf16(fa0, b, acc[ct], 0, 0, 0); \
        }                                                                       \
    }

    NK_H(o0, 0);              // k  0..31 : nf 0..31
    NK_H(o1, 1);              // k 32..63 : nf 32..63
    NK_A(o0, 2);              // k 64..95 : agg/cnt 0..31
    NK_A(o1, 3);              // k 96..127: agg/cnt 32..63
#undef NK_H
#undef NK_A

    // bias + tanh GELU -> h_lds (bf16), certified C/D mapping
#pragma unroll
    for (int ct = 0; ct < 8; ++ct) {
        const int col = ct * 16 + lo;
        const float bb = b1[col];
#pragma unroll
        for (int r = 0; r < 4; ++r) {
            float x = acc[ct][r] + bb;
            h_lds[wave * 16 + hi * 4 + r][col] = f2bf(gelu_fast(x));
        }
    }
    // no barrier: all LDS traffic below stays within this wave's 16-row stripe

    f32x4 acc2[4];
#pragma unroll
    for (int j = 0; j < 4; ++j)
#pragma unroll
        for (int q = 0; q < 4; ++q) acc2[j][q] = 0.0f;
#pragma unroll
    for (int ks = 0; ks < 4; ++ks) {
        const int k0 = ks * 32 + hi * 8;
        s16x8 a0 = *(const s16x8*)&h_lds[wave * 16 + lo][k0];
#pragma unroll
        for (int ct = 0; ct < 4; ++ct) {
            s16x8 b = *(const s16x8*)&w2s[((ks * 4 + ct) << 9) + lane * 8];
            acc2[ct] = __builtin_amdgcn_mfma_f32_16x16x32_bf16(a0, b, acc2[ct], 0, 0, 0);
        }
    }

    float (*u_lds)[68] = (float (*)[68])h_lds;   // 64*68*4 = 17408 B, exact alias
#pragma unroll
    for (int ct = 0; ct < 4; ++ct)
#pragma unroll
        for (int r = 0; r < 4; ++r)
            u_lds[wave * 16 + hi * 4 + r][ct * 16 + lo] = acc2[ct][r];

    // certified SERIAL epilogue: lane = output column; residual from nf (f32)
    const float b2v = b2[lane], gmv = gamma[lane], btv = beta[lane];
#pragma unroll 4
    for (int e = 0; e < 16; ++e) {
        const int er   = wave * 16 + e;
        const int nrow = blockIdx.x * 64 + er;
        if (nrow < NN) {                             // wave-uniform guard
            float o = u_lds[er][lane] + b2v + nf[(size_t)nrow * 64 + lane];
            float s = o, s2 = o * o;
#pragma unroll
            for (int m = 1; m < 64; m <<= 1) { s += __shfl_xor(s, m); s2 += __shfl_xor(s2, m); }
            const float mean = s * 0.015625f;
            const float var  = s2 * 0.015625f - mean * mean;
            const float rs   = rsqrtf(var + 1e-5f);
            nout[(size_t)nrow * 64 + lane] = (o - mean) * rs * gmv + btv;
        }
    }
}

extern "C" void kernel_launch(void* const* d_in, const int* in_sizes, int n_in,
                              void* d_out, int out_size, void* d_ws, size_t ws_size,
                              hipStream_t stream)
{
    const float* nf  = (const float*)d_in[0];
    const int*   ei  = (const int*)d_in[1];
    const float* ef  = (const float*)d_in[2];
    const float* ew1 = (const float*)d_in[3];
    const float* eb1 = (const float*)d_in[4];
    const float* ew2 = (const float*)d_in[5];
    const float* eb2 = (const float*)d_in[6];
    const float* nw1 = (const float*)d_in[7];
    const float* nb1 = (const float*)d_in[8];
    const float* nw2 = (const float*)d_in[9];
    const float* nb2 = (const float*)d_in[10];
    const float* eg  = (const float*)d_in[11];
    const float* ebt = (const float*)d_in[12];
    const float* ng  = (const float*)d_in[13];
    const float* nbt = (const float*)d_in[14];

    float* node_out = (float*)d_out;
    float* edge_out = node_out + (size_t)NN * 64;
    char*  ws    = (char*)d_ws;
    float* cnt   = (float*)(ws);             // 200000 B (pad 200704)
    short* w1f   = (short*)(ws + 200704);    // 49152 B -> 249856
    short* w2f   = (short*)(ws + 249856);    // 16384 B -> 266240
    short* w1nf  = (short*)(ws + 266240);    // 32768 B -> 299008
    short* w2nf  = (short*)(ws + 299008);    // 16384 B -> 315392
    short* nfh   = (short*)(ws + 315392);    // 6.4 MB  -> 6,715,392
    short* aggh  = (short*)(ws + 6715392);   // 6.4 MB  -> 13,115,392

    prep_e<<<(NN * 64 + 255) / 256, 256, 0, stream>>>(nf, ew1, ew2, nw1, nw2,
                                                      nfh, w1f, w2f, w1nf, w2nf,
                                                      aggh, cnt);
    edge_k<<<NE / 256, 1024, 0, stream>>>(nfh, ei, ef, w1f, eb1, w2f, eb2, eg, ebt,
                                          edge_out, aggh, cnt);
    node_k<<<(NN + 63) / 64, 256, 0, stream>>>(nfh, nf, aggh, cnt, w1nf, nb1,
                                               w2nf, nb2, ng, nbt, node_out);
}